// Round 8
// baseline (298.751 us; speedup 1.0000x reference)
//
#include <hip/hip_runtime.h>
#include <hip/hip_bf16.h>
#include <stdint.h>

// ---------- types ----------
typedef __bf16 bf16x8 __attribute__((ext_vector_type(8)));
typedef float  f32x4  __attribute__((ext_vector_type(4)));
typedef float  f32x16 __attribute__((ext_vector_type(16)));

#define AS1(p) (const __attribute__((address_space(1))) uint32_t*)(p)
#define AS3(p) (__attribute__((address_space(3))) uint32_t*)(p)

__device__ __forceinline__ unsigned short f2bf(float f) {
  uint32_t u = __builtin_bit_cast(uint32_t, f);
  u = (u + 0x7fffu + ((u >> 16) & 1u)) >> 16;
  return (unsigned short)u;
}

__device__ __forceinline__ bf16x8 ldsv8(const unsigned short* p) {
  return __builtin_bit_cast(bf16x8, *(const uint4*)p);
}

__device__ __forceinline__ uint32_t cvtpk(float lo, float hi) {
  uint32_t d;
  asm("v_cvt_pk_bf16_f32 %0, %1, %2" : "=v"(d) : "v"(lo), "v"(hi));
  return d;
}

// v_permlane32_swap_b32: a's upper 32 lanes <-> b's lower 32 lanes.
__device__ __forceinline__ void plswap(uint32_t& a, uint32_t& b) {
  asm volatile("v_permlane32_swap_b32 %0, %1" : "+v"(a), "+v"(b));
}

// ---------- fp32 -> bf16 convert (8 elems/thread) ----------
__global__ void cvt_kernel(const float* __restrict__ in,
                           unsigned short* __restrict__ out, int n8) {
  int stride = gridDim.x * blockDim.x;
  for (int i = blockIdx.x * blockDim.x + threadIdx.x; i < n8; i += stride) {
    const float4* p = (const float4*)in + 2 * (size_t)i;
    float4 a = p[0], b = p[1];
    uint4 o;
    o.x = (uint32_t)f2bf(a.x) | ((uint32_t)f2bf(a.y) << 16);
    o.y = (uint32_t)f2bf(a.z) | ((uint32_t)f2bf(a.w) << 16);
    o.z = (uint32_t)f2bf(b.x) | ((uint32_t)f2bf(b.y) << 16);
    o.w = (uint32_t)f2bf(b.z) | ((uint32_t)f2bf(b.w) << 16);
    ((uint4*)out)[i] = o;
  }
}

// ---------- 4 weight matrices in one launch: grid.y selects the pair ----------
__global__ void cvt_w_kernel(const float* __restrict__ w0, const float* __restrict__ w1,
                             const float* __restrict__ w2, const float* __restrict__ w3,
                             unsigned short* __restrict__ o0, unsigned short* __restrict__ o1,
                             unsigned short* __restrict__ o2, unsigned short* __restrict__ o3,
                             int n8) {
  const float* in = (blockIdx.y == 0) ? w0 : (blockIdx.y == 1) ? w1 : (blockIdx.y == 2) ? w2 : w3;
  unsigned short* out = (blockIdx.y == 0) ? o0 : (blockIdx.y == 1) ? o1 : (blockIdx.y == 2) ? o2 : o3;
  int stride = gridDim.x * blockDim.x;
  for (int i = blockIdx.x * blockDim.x + threadIdx.x; i < n8; i += stride) {
    const float4* p = (const float4*)in + 2 * (size_t)i;
    float4 a = p[0], b = p[1];
    uint4 o;
    o.x = (uint32_t)f2bf(a.x) | ((uint32_t)f2bf(a.y) << 16);
    o.y = (uint32_t)f2bf(a.z) | ((uint32_t)f2bf(a.w) << 16);
    o.z = (uint32_t)f2bf(b.x) | ((uint32_t)f2bf(b.y) << 16);
    o.w = (uint32_t)f2bf(b.z) | ((uint32_t)f2bf(b.w) << 16);
    ((uint4*)out)[i] = o;
  }
}

// ---------- FUSED QKV projection GEMM: stages X once, 3 weight tiles, 48 MFMA/K-step ----------
// X: [8192,1024] bf16; Wq/Wk/Wv: [1024,1024] bf16 [N,K].
// Outputs: Q (scaled 0.125) -> [B,H,S,DK]; K -> [B,H,S,DK]; V -> [B,H,DK,S] transposed.
__global__ __launch_bounds__(256) void gemm_qkv_kernel(
    const unsigned short* __restrict__ X,
    const unsigned short* __restrict__ Wq,
    const unsigned short* __restrict__ Wk,
    const unsigned short* __restrict__ Wv,
    unsigned short* __restrict__ Qo,
    unsigned short* __restrict__ Ko,
    unsigned short* __restrict__ Vt) {
  __shared__ unsigned short lsA[128 * 32];
  __shared__ unsigned short lsB[3][128 * 32];
  const int m0 = blockIdx.y * 128;
  const int n0 = blockIdx.x * 128;
  const int tid = threadIdx.x;
  const int wid = tid >> 6, lane = tid & 63;
  const int wm = wid >> 1, wn = wid & 1;
  const int lrow = lane & 15, lhi = lane >> 4;

  f32x4 acc[3][4][4];
#pragma unroll
  for (int z = 0; z < 3; ++z)
#pragma unroll
    for (int i = 0; i < 4; ++i)
#pragma unroll
      for (int j = 0; j < 4; ++j) acc[z][i][j] = f32x4{0.f, 0.f, 0.f, 0.f};

  for (int kt = 0; kt < 1024; kt += 32) {
#pragma unroll
    for (int c = 0; c < 2; ++c) {
      const int idx = wid * 64 + c * 256 + lane;           // chunk 0..511
      const uint32_t off = (uint32_t)(idx * 16);           // byte in 8KB tile
      const uint32_t row = off >> 6, col = (off & 63) >> 1;
      const unsigned short* ga = X + (size_t)(m0 + row) * 1024 + kt + col;
      const size_t wof = (size_t)(n0 + row) * 1024 + kt + col;
      __builtin_amdgcn_global_load_lds(AS1(ga), AS3(lsA + idx * 8), 16, 0, 0);
      __builtin_amdgcn_global_load_lds(AS1(Wq + wof), AS3(lsB[0] + idx * 8), 16, 0, 0);
      __builtin_amdgcn_global_load_lds(AS1(Wk + wof), AS3(lsB[1] + idx * 8), 16, 0, 0);
      __builtin_amdgcn_global_load_lds(AS1(Wv + wof), AS3(lsB[2] + idx * 8), 16, 0, 0);
    }
    __syncthreads();
    bf16x8 af[4];
#pragma unroll
    for (int i = 0; i < 4; ++i)
      af[i] = ldsv8(&lsA[(wm * 64 + i * 16 + lrow) * 32 + lhi * 8]);
#pragma unroll
    for (int z = 0; z < 3; ++z)
#pragma unroll
      for (int j = 0; j < 4; ++j) {
        bf16x8 bfv = ldsv8(&lsB[z][(wn * 64 + j * 16 + lrow) * 32 + lhi * 8]);
#pragma unroll
        for (int i = 0; i < 4; ++i)
          acc[z][i][j] = __builtin_amdgcn_mfma_f32_16x16x32_bf16(af[i], bfv, acc[z][i][j], 0, 0, 0);
      }
    __syncthreads();
  }

#pragma unroll
  for (int z = 0; z < 3; ++z) {
    const float scale = (z == 0) ? 0.125f : 1.0f;
#pragma unroll
    for (int i = 0; i < 4; ++i)
#pragma unroll
      for (int j = 0; j < 4; ++j)
#pragma unroll
        for (int r = 0; r < 4; ++r) {
          int m = m0 + wm * 64 + i * 16 + lhi * 4 + r;   // row in [0,8192)
          int n = n0 + wn * 64 + j * 16 + lrow;          // col in [0,1024)
          unsigned short hv = f2bf(acc[z][i][j][r] * scale);
          int b = m >> 11, s = m & 2047, h = n >> 6, dk = n & 63;
          if (z == 2) {
            Vt[((size_t)(b * 16 + h) * 64 + dk) * 2048 + s] = hv;
          } else if (z == 0) {
            Qo[((size_t)(b * 16 + h) * 2048 + s) * 64 + dk] = hv;
          } else {
            Ko[((size_t)(b * 16 + h) * 2048 + s) * 64 + dk] = hv;
          }
        }
  }
}

// ---------- output GEMM: out = attn @ Wo^T (fp32 out) ----------
__global__ __launch_bounds__(256) void gemm_ao_kernel(
    const unsigned short* __restrict__ A,
    const unsigned short* __restrict__ Bt,
    float* __restrict__ C) {
  __shared__ unsigned short lsA[128 * 32];
  __shared__ unsigned short lsB[128 * 32];
  const int m0 = blockIdx.y * 128;
  const int n0 = blockIdx.x * 128;
  const int tid = threadIdx.x;
  const int wid = tid >> 6, lane = tid & 63;
  const int wm = wid >> 1, wn = wid & 1;
  const int lrow = lane & 15, lhi = lane >> 4;

  f32x4 acc[4][4];
#pragma unroll
  for (int i = 0; i < 4; ++i)
#pragma unroll
    for (int j = 0; j < 4; ++j) acc[i][j] = f32x4{0.f, 0.f, 0.f, 0.f};

  for (int kt = 0; kt < 1024; kt += 32) {
#pragma unroll
    for (int c = 0; c < 2; ++c) {
      const uint32_t off = (uint32_t)((wid * 64 + c * 256 + lane) * 16);
      const uint32_t row = off >> 6, col = (off & 63) >> 1;
      const unsigned short* ga = A + (size_t)(m0 + row) * 1024 + kt + col;
      const unsigned short* gb = Bt + (size_t)(n0 + row) * 1024 + kt + col;
      __builtin_amdgcn_global_load_lds(AS1(ga), AS3(lsA + (wid * 64 + c * 256) * 8), 16, 0, 0);
      __builtin_amdgcn_global_load_lds(AS1(gb), AS3(lsB + (wid * 64 + c * 256) * 8), 16, 0, 0);
    }
    __syncthreads();
    bf16x8 af[4], bfv[4];
#pragma unroll
    for (int i = 0; i < 4; ++i)
      af[i] = ldsv8(&lsA[(wm * 64 + i * 16 + lrow) * 32 + lhi * 8]);
#pragma unroll
    for (int j = 0; j < 4; ++j)
      bfv[j] = ldsv8(&lsB[(wn * 64 + j * 16 + lrow) * 32 + lhi * 8]);
#pragma unroll
    for (int i = 0; i < 4; ++i)
#pragma unroll
      for (int j = 0; j < 4; ++j)
        acc[i][j] = __builtin_amdgcn_mfma_f32_16x16x32_bf16(af[i], bfv[j], acc[i][j], 0, 0, 0);
    __syncthreads();
  }

#pragma unroll
  for (int i = 0; i < 4; ++i)
#pragma unroll
    for (int j = 0; j < 4; ++j)
#pragma unroll
      for (int r = 0; r < 4; ++r) {
        int m = m0 + wm * 64 + i * 16 + lhi * 4 + r;
        int n = n0 + wn * 64 + j * 16 + lrow;
        C[(size_t)m * 1024 + n] = acc[i][j][r];
      }
}

// ---------- flash attention: swapped 32x32 MFMA, in-register softmax ----------
// Grid: (64 bh FAST, 16 qsy) so gid%8 = bh%8 -> every qs-class spreads over all 8 XCDs.
__global__ __launch_bounds__(256, 3) void fattn_kernel(
    const unsigned short* __restrict__ Q,
    const unsigned short* __restrict__ K,
    const unsigned short* __restrict__ Vt,
    unsigned short* __restrict__ attn) {
  __shared__ unsigned short lsK[64 * 64];     // [key][d], XOR-swizzled
  __shared__ unsigned short lsV[64 * 64];     // [d][key], XOR-swizzled
  __shared__ unsigned short lsE[4][32][72];   // per-wave epilogue transpose

  const int qs = 15 - (int)blockIdx.y;        // heavy classes launch first
  const int bh = blockIdx.x;
  const int tid = threadIdx.x, wid = tid >> 6, lane = tid & 63;
  const int ql = lane & 31, hi = lane >> 5;
  const int qwb = qs * 128 + wid * 32;        // wave's q base
  const int qg = qwb + ql;                    // this lane's q row
  const int kbmax = 2 * qs + 1;

  const unsigned short* Qbh = Q + (size_t)bh * 2048 * 64;
  const unsigned short* Kbh = K + (size_t)bh * 2048 * 64;
  const unsigned short* Vbh = Vt + (size_t)bh * 64 * 2048;

  bf16x8 qf[4];
#pragma unroll
  for (int dd = 0; dd < 4; ++dd)
    qf[dd] = __builtin_bit_cast(
        bf16x8, *(const uint4*)&Qbh[(size_t)qg * 64 + dd * 16 + hi * 8]);

  f32x16 oacc[2];
#pragma unroll
  for (int dt = 0; dt < 2; ++dt)
#pragma unroll
    for (int r = 0; r < 16; ++r) oacc[dt][r] = 0.f;
  float m_run = -1e38f, l_run = 0.f;

  const int sr = tid >> 3;                    // 0..31
  const int scb = (tid & 7) << 4;             // byte col in 128B row
  const int ssw = (scb ^ ((sr & 7) << 4)) >> 1;  // swizzled ushort col
  unsigned short* dK0 = lsK + sr * 64 + ssw;
  unsigned short* dK1 = lsK + (sr + 32) * 64 + ssw;
  unsigned short* dV0 = lsV + sr * 64 + ssw;
  unsigned short* dV1 = lsV + (sr + 32) * 64 + ssw;
  const int sc = scb >> 1;                    // source ushort col

  uint4 rk0 = *(const uint4*)&Kbh[(size_t)sr * 64 + sc];
  uint4 rk1 = *(const uint4*)&Kbh[(size_t)(sr + 32) * 64 + sc];
  uint4 rv0 = *(const uint4*)&Vbh[(size_t)sr * 2048 + sc];
  uint4 rv1 = *(const uint4*)&Vbh[(size_t)(sr + 32) * 2048 + sc];

  const int swzm = (ql & 7) << 4;

  for (int kb = 0; kb <= kbmax; ++kb) {
    *(uint4*)dK0 = rk0;
    *(uint4*)dK1 = rk1;
    *(uint4*)dV0 = rv0;
    *(uint4*)dV1 = rv1;
    __syncthreads();
    if (kb < kbmax) {  // prefetch next tile
      const int k0n = (kb + 1) * 64;
      rk0 = *(const uint4*)&Kbh[(size_t)(k0n + sr) * 64 + sc];
      rk1 = *(const uint4*)&Kbh[(size_t)(k0n + sr + 32) * 64 + sc];
      rv0 = *(const uint4*)&Vbh[(size_t)sr * 2048 + k0n + sc];
      rv1 = *(const uint4*)&Vbh[(size_t)(sr + 32) * 2048 + k0n + sc];
    }
    if (kb * 64 <= qwb + 31) {  // wave-uniform causal skip
      f32x16 sacc[2];
#pragma unroll
      for (int kt = 0; kt < 2; ++kt)
#pragma unroll
        for (int r = 0; r < 16; ++r) sacc[kt][r] = 0.f;
      __builtin_amdgcn_s_setprio(1);
#pragma unroll
      for (int kt = 0; kt < 2; ++kt)
#pragma unroll
        for (int dd = 0; dd < 4; ++dd) {
          const int col = (((dd << 5) | (hi << 4)) ^ swzm) >> 1;
          bf16x8 kf = ldsv8(&lsK[(kt * 32 + ql) * 64 + col]);
          sacc[kt] = __builtin_amdgcn_mfma_f32_32x32x16_bf16(kf, qf[dd], sacc[kt], 0, 0, 0);
        }
      __builtin_amdgcn_s_setprio(0);
      if (kb * 64 + 63 > qwb) {
#pragma unroll
        for (int kt = 0; kt < 2; ++kt)
#pragma unroll
          for (int r = 0; r < 16; ++r) {
            int key = kb * 64 + kt * 32 + (r & 3) + 8 * (r >> 2) + 4 * hi;
            if (key > qg) sacc[kt][r] = -1e38f;
          }
      }
      // ---- online softmax with defer-max (T13, THR=8)
      float t16[16];
#pragma unroll
      for (int i = 0; i < 16; ++i) t16[i] = fmaxf(sacc[0][i], sacc[1][i]);
#pragma unroll
      for (int i = 0; i < 8; ++i) t16[i] = fmaxf(t16[i], t16[i + 8]);
#pragma unroll
      for (int i = 0; i < 4; ++i) t16[i] = fmaxf(t16[i], t16[i + 4]);
      float mx = fmaxf(fmaxf(t16[0], t16[1]), fmaxf(t16[2], t16[3]));
      mx = fmaxf(mx, __shfl_xor(mx, 32));
      if (!__all(mx <= m_run + 8.0f)) {
        const float mnew = fmaxf(m_run, mx);
        const float alpha = exp2f((m_run - mnew) * 1.44269504f);
        m_run = mnew;
        l_run *= alpha;
#pragma unroll
        for (int dt = 0; dt < 2; ++dt)
#pragma unroll
          for (int r = 0; r < 16; ++r) oacc[dt][r] *= alpha;
      }
#pragma unroll
      for (int kt = 0; kt < 2; ++kt)
#pragma unroll
        for (int r = 0; r < 16; ++r)
          sacc[kt][r] = exp2f((sacc[kt][r] - m_run) * 1.44269504f);
      float s16[16];
#pragma unroll
      for (int i = 0; i < 16; ++i) s16[i] = sacc[0][i] + sacc[1][i];
#pragma unroll
      for (int i = 0; i < 8; ++i) s16[i] += s16[i + 8];
#pragma unroll
      for (int i = 0; i < 4; ++i) s16[i] += s16[i + 4];
      float psum = (s16[0] + s16[1]) + (s16[2] + s16[3]);
      psum += __shfl_xor(psum, 32);
      l_run += psum;
      // ---- P pack + swapped PV
#pragma unroll
      for (int ks = 0; ks < 4; ++ks) {
        const int kt = ks >> 1, s8 = (ks & 1) * 8;
        uint32_t d00 = cvtpk(sacc[kt][s8 + 0], sacc[kt][s8 + 1]);
        uint32_t d01 = cvtpk(sacc[kt][s8 + 2], sacc[kt][s8 + 3]);
        uint32_t d10 = cvtpk(sacc[kt][s8 + 4], sacc[kt][s8 + 5]);
        uint32_t d11 = cvtpk(sacc[kt][s8 + 6], sacc[kt][s8 + 7]);
        plswap(d00, d10);
        plswap(d01, d11);
        uint4 pw;
        pw.x = d00; pw.y = d01; pw.z = d10; pw.w = d11;
        bf16x8 pb = __builtin_bit_cast(bf16x8, pw);
        __builtin_amdgcn_s_setprio(1);
#pragma unroll
        for (int dt = 0; dt < 2; ++dt) {
          const int col = (((ks << 5) | (hi << 4)) ^ swzm) >> 1;
          bf16x8 vf = ldsv8(&lsV[(dt * 32 + ql) * 64 + col]);
          oacc[dt] = __builtin_amdgcn_mfma_f32_32x32x16_bf16(vf, pb, oacc[dt], 0, 0, 0);
        }
        __builtin_amdgcn_s_setprio(0);
      }
    }
    __syncthreads();
  }

  // ---- epilogue: O^T -> LDS transpose -> coalesced global store
  const float inv = 1.0f / l_run;
  const int b = bh >> 4, h = bh & 15;
#pragma unroll
  for (int dt = 0; dt < 2; ++dt)
#pragma unroll
    for (int r = 0; r < 16; r += 2) {
      int d0 = dt * 32 + (r & 3) + 8 * (r >> 2) + 4 * hi;
      uint32_t dw = cvtpk(oacc[dt][r] * inv, oacc[dt][r + 1] * inv);
      *(uint32_t*)&lsE[wid][ql][d0] = dw;
    }
#pragma unroll
  for (int p = 0; p < 4; ++p) {
    int id = p * 64 + lane;
    int rq = id >> 3, ch = (id & 7) * 8;
    uint4 vv = *(const uint4*)&lsE[wid][rq][ch];
    *(uint4*)&attn[((size_t)(b * 2048 + qwb + rq)) * 1024 + h * 64 + ch] = vv;
  }
}

// ---------- workspace layout (bytes) ----------
//  xb @0 16MB | wqb @16MB 2MB | wkb @18MB 2MB | wvb @20MB 2MB | wob @22MB 2MB
//  Qb @24MB 16MB | Kb @40MB 16MB | Vtb @56MB 16MB | attnb @72MB 16MB

extern "C" void kernel_launch(void* const* d_in, const int* in_sizes, int n_in,
                              void* d_out, int out_size, void* d_ws, size_t ws_size,
                              hipStream_t stream) {
  const float* x = (const float*)d_in[0];
  const float* wq = (const float*)d_in[1];
  const float* wk = (const float*)d_in[2];
  const float* wv = (const float*)d_in[3];
  const float* wo = (const float*)d_in[4];
  float* out = (float*)d_out;

  char* ws = (char*)d_ws;
  unsigned short* xb   = (unsigned short*)(ws + 0);
  unsigned short* wqb  = (unsigned short*)(ws + 16777216);
  unsigned short* wkb  = (unsigned short*)(ws + 18874368);
  unsigned short* wvb  = (unsigned short*)(ws + 20971520);
  unsigned short* wob  = (unsigned short*)(ws + 23068672);
  unsigned short* Qb   = (unsigned short*)(ws + 25165824);
  unsigned short* Kb   = (unsigned short*)(ws + 41943040);
  unsigned short* Vtb  = (unsigned short*)(ws + 58720256);
  unsigned short* attb = (unsigned short*)(ws + 75497472);

  cvt_kernel<<<2048, 256, 0, stream>>>(x, xb, 1048576);
  cvt_w_kernel<<<dim3(256, 4), 256, 0, stream>>>(wq, wk, wv, wo, wqb, wkb, wvb, wob, 131072);

  gemm_qkv_kernel<<<dim3(8, 64), 256, 0, stream>>>(xb, wqb, wkb, wvb, Qb, Kb, Vtb);
  fattn_kernel<<<dim3(64, 16), 256, 0, stream>>>(Qb, Kb, Vtb, attb);
  gemm_ao_kernel<<<dim3(8, 64), 256, 0, stream>>>(attb, wob, out);
}

// Round 9
// 280.194 us; speedup vs baseline: 1.0662x; 1.0662x over previous
//
#include <hip/hip_runtime.h>
#include <hip/hip_bf16.h>
#include <stdint.h>

// ---------- types ----------
typedef __bf16 bf16x8 __attribute__((ext_vector_type(8)));
typedef float  f32x4  __attribute__((ext_vector_type(4)));
typedef float  f32x16 __attribute__((ext_vector_type(16)));

#define AS1(p) (const __attribute__((address_space(1))) uint32_t*)(p)
#define AS3(p) (__attribute__((address_space(3))) uint32_t*)(p)

__device__ __forceinline__ unsigned short f2bf(float f) {
  uint32_t u = __builtin_bit_cast(uint32_t, f);
  u = (u + 0x7fffu + ((u >> 16) & 1u)) >> 16;
  return (unsigned short)u;
}

__device__ __forceinline__ bf16x8 ldsv8(const unsigned short* p) {
  return __builtin_bit_cast(bf16x8, *(const uint4*)p);
}

__device__ __forceinline__ uint32_t cvtpk(float lo, float hi) {
  uint32_t d;
  asm("v_cvt_pk_bf16_f32 %0, %1, %2" : "=v"(d) : "v"(lo), "v"(hi));
  return d;
}

// v_permlane32_swap_b32: a's upper 32 lanes <-> b's lower 32 lanes.
__device__ __forceinline__ void plswap(uint32_t& a, uint32_t& b) {
  asm volatile("v_permlane32_swap_b32 %0, %1" : "+v"(a), "+v"(b));
}

// ---------- fp32 -> bf16 convert (8 elems/thread) ----------
__global__ void cvt_kernel(const float* __restrict__ in,
                           unsigned short* __restrict__ out, int n8) {
  int stride = gridDim.x * blockDim.x;
  for (int i = blockIdx.x * blockDim.x + threadIdx.x; i < n8; i += stride) {
    const float4* p = (const float4*)in + 2 * (size_t)i;
    float4 a = p[0], b = p[1];
    uint4 o;
    o.x = (uint32_t)f2bf(a.x) | ((uint32_t)f2bf(a.y) << 16);
    o.y = (uint32_t)f2bf(a.z) | ((uint32_t)f2bf(a.w) << 16);
    o.z = (uint32_t)f2bf(b.x) | ((uint32_t)f2bf(b.y) << 16);
    o.w = (uint32_t)f2bf(b.z) | ((uint32_t)f2bf(b.w) << 16);
    ((uint4*)out)[i] = o;
  }
}

// ---------- 4 weight matrices in one launch: grid.y selects the pair ----------
__global__ void cvt_w_kernel(const float* __restrict__ w0, const float* __restrict__ w1,
                             const float* __restrict__ w2, const float* __restrict__ w3,
                             unsigned short* __restrict__ o0, unsigned short* __restrict__ o1,
                             unsigned short* __restrict__ o2, unsigned short* __restrict__ o3,
                             int n8) {
  const float* in = (blockIdx.y == 0) ? w0 : (blockIdx.y == 1) ? w1 : (blockIdx.y == 2) ? w2 : w3;
  unsigned short* out = (blockIdx.y == 0) ? o0 : (blockIdx.y == 1) ? o1 : (blockIdx.y == 2) ? o2 : o3;
  int stride = gridDim.x * blockDim.x;
  for (int i = blockIdx.x * blockDim.x + threadIdx.x; i < n8; i += stride) {
    const float4* p = (const float4*)in + 2 * (size_t)i;
    float4 a = p[0], b = p[1];
    uint4 o;
    o.x = (uint32_t)f2bf(a.x) | ((uint32_t)f2bf(a.y) << 16);
    o.y = (uint32_t)f2bf(a.z) | ((uint32_t)f2bf(a.w) << 16);
    o.z = (uint32_t)f2bf(b.x) | ((uint32_t)f2bf(b.y) << 16);
    o.w = (uint32_t)f2bf(b.z) | ((uint32_t)f2bf(b.w) << 16);
    ((uint4*)out)[i] = o;
  }
}

// ---------- QKV projection GEMM (UNFUSED, round-5 measured 93.7us): z selects W ----------
__global__ __launch_bounds__(256) void gemm_qkv_kernel(
    const unsigned short* __restrict__ X,
    const unsigned short* __restrict__ Wq,
    const unsigned short* __restrict__ Wk,
    const unsigned short* __restrict__ Wv,
    unsigned short* __restrict__ Qo,
    unsigned short* __restrict__ Ko,
    unsigned short* __restrict__ Vt) {
  __shared__ unsigned short lsA[128 * 32];
  __shared__ unsigned short lsB[128 * 32];
  const int z = blockIdx.z;
  const unsigned short* Bt = (z == 0) ? Wq : (z == 1) ? Wk : Wv;
  const int m0 = blockIdx.y * 128;
  const int n0 = blockIdx.x * 128;
  const int tid = threadIdx.x;
  const int wid = tid >> 6, lane = tid & 63;
  const int wm = wid >> 1, wn = wid & 1;
  const int lrow = lane & 15, lhi = lane >> 4;

  f32x4 acc[4][4];
#pragma unroll
  for (int i = 0; i < 4; ++i)
#pragma unroll
    for (int j = 0; j < 4; ++j) acc[i][j] = f32x4{0.f, 0.f, 0.f, 0.f};

  for (int kt = 0; kt < 1024; kt += 32) {
#pragma unroll
    for (int c = 0; c < 2; ++c) {
      const uint32_t off = (uint32_t)((wid * 64 + c * 256 + lane) * 16);
      const uint32_t row = off >> 6, col = (off & 63) >> 1;
      const unsigned short* ga = X + (size_t)(m0 + row) * 1024 + kt + col;
      const unsigned short* gb = Bt + (size_t)(n0 + row) * 1024 + kt + col;
      __builtin_amdgcn_global_load_lds(AS1(ga), AS3(lsA + (wid * 64 + c * 256) * 8), 16, 0, 0);
      __builtin_amdgcn_global_load_lds(AS1(gb), AS3(lsB + (wid * 64 + c * 256) * 8), 16, 0, 0);
    }
    __syncthreads();
    bf16x8 af[4], bfv[4];
#pragma unroll
    for (int i = 0; i < 4; ++i)
      af[i] = ldsv8(&lsA[(wm * 64 + i * 16 + lrow) * 32 + lhi * 8]);
#pragma unroll
    for (int j = 0; j < 4; ++j)
      bfv[j] = ldsv8(&lsB[(wn * 64 + j * 16 + lrow) * 32 + lhi * 8]);
#pragma unroll
    for (int i = 0; i < 4; ++i)
#pragma unroll
      for (int j = 0; j < 4; ++j)
        acc[i][j] = __builtin_amdgcn_mfma_f32_16x16x32_bf16(af[i], bfv[j], acc[i][j], 0, 0, 0);
    __syncthreads();
  }

  const float scale = (z == 0) ? 0.125f : 1.0f;
#pragma unroll
  for (int i = 0; i < 4; ++i)
#pragma unroll
    for (int j = 0; j < 4; ++j)
#pragma unroll
      for (int r = 0; r < 4; ++r) {
        int m = m0 + wm * 64 + i * 16 + lhi * 4 + r;
        int n = n0 + wn * 64 + j * 16 + lrow;
        unsigned short hv = f2bf(acc[i][j][r] * scale);
        int b = m >> 11, s = m & 2047, h = n >> 6, dk = n & 63;
        if (z == 2) {
          Vt[((size_t)(b * 16 + h) * 64 + dk) * 2048 + s] = hv;
        } else if (z == 0) {
          Qo[((size_t)(b * 16 + h) * 2048 + s) * 64 + dk] = hv;
        } else {
          Ko[((size_t)(b * 16 + h) * 2048 + s) * 64 + dk] = hv;
        }
      }
}

// ---------- output GEMM: out = attn @ Wo^T (fp32 out) ----------
__global__ __launch_bounds__(256) void gemm_ao_kernel(
    const unsigned short* __restrict__ A,
    const unsigned short* __restrict__ Bt,
    float* __restrict__ C) {
  __shared__ unsigned short lsA[128 * 32];
  __shared__ unsigned short lsB[128 * 32];
  const int m0 = blockIdx.y * 128;
  const int n0 = blockIdx.x * 128;
  const int tid = threadIdx.x;
  const int wid = tid >> 6, lane = tid & 63;
  const int wm = wid >> 1, wn = wid & 1;
  const int lrow = lane & 15, lhi = lane >> 4;

  f32x4 acc[4][4];
#pragma unroll
  for (int i = 0; i < 4; ++i)
#pragma unroll
    for (int j = 0; j < 4; ++j) acc[i][j] = f32x4{0.f, 0.f, 0.f, 0.f};

  for (int kt = 0; kt < 1024; kt += 32) {
#pragma unroll
    for (int c = 0; c < 2; ++c) {
      const uint32_t off = (uint32_t)((wid * 64 + c * 256 + lane) * 16);
      const uint32_t row = off >> 6, col = (off & 63) >> 1;
      const unsigned short* ga = A + (size_t)(m0 + row) * 1024 + kt + col;
      const unsigned short* gb = Bt + (size_t)(n0 + row) * 1024 + kt + col;
      __builtin_amdgcn_global_load_lds(AS1(ga), AS3(lsA + (wid * 64 + c * 256) * 8), 16, 0, 0);
      __builtin_amdgcn_global_load_lds(AS1(gb), AS3(lsB + (wid * 64 + c * 256) * 8), 16, 0, 0);
    }
    __syncthreads();
    bf16x8 af[4], bfv[4];
#pragma unroll
    for (int i = 0; i < 4; ++i)
      af[i] = ldsv8(&lsA[(wm * 64 + i * 16 + lrow) * 32 + lhi * 8]);
#pragma unroll
    for (int j = 0; j < 4; ++j)
      bfv[j] = ldsv8(&lsB[(wn * 64 + j * 16 + lrow) * 32 + lhi * 8]);
#pragma unroll
    for (int i = 0; i < 4; ++i)
#pragma unroll
      for (int j = 0; j < 4; ++j)
        acc[i][j] = __builtin_amdgcn_mfma_f32_16x16x32_bf16(af[i], bfv[j], acc[i][j], 0, 0, 0);
    __syncthreads();
  }

#pragma unroll
  for (int i = 0; i < 4; ++i)
#pragma unroll
    for (int j = 0; j < 4; ++j)
#pragma unroll
      for (int r = 0; r < 4; ++r) {
        int m = m0 + wm * 64 + i * 16 + lhi * 4 + r;
        int n = n0 + wn * 64 + j * 16 + lrow;
        C[(size_t)m * 1024 + n] = acc[i][j][r];
      }
}

// ---------- flash attention: swapped 32x32 MFMA, dbuf K/V, ONE barrier per KV tile ----------
// Grid: (64 bh FAST, 16 qsy) -> gid%8 = bh%8 spreads each causal class over all XCDs.
// LDS: lsKV[0..1]=K bufs, [2..3]=V bufs (32KB); epilogue transpose aliases the same space.
__global__ __launch_bounds__(256, 3) void fattn_kernel(
    const unsigned short* __restrict__ Q,
    const unsigned short* __restrict__ K,
    const unsigned short* __restrict__ Vt,
    unsigned short* __restrict__ attn) {
  __shared__ unsigned short lsKV[4][64 * 64];

  const int qs = 15 - (int)blockIdx.y;        // heavy classes launch first
  const int bh = blockIdx.x;
  const int tid = threadIdx.x, wid = tid >> 6, lane = tid & 63;
  const int ql = lane & 31, hi = lane >> 5;
  const int qwb = qs * 128 + wid * 32;        // wave's q base
  const int qg = qwb + ql;                    // this lane's q row
  const int kbmax = 2 * qs + 1;

  const unsigned short* Qbh = Q + (size_t)bh * 2048 * 64;
  const unsigned short* Kbh = K + (size_t)bh * 2048 * 64;
  const unsigned short* Vbh = Vt + (size_t)bh * 64 * 2048;

  bf16x8 qf[4];
#pragma unroll
  for (int dd = 0; dd < 4; ++dd)
    qf[dd] = __builtin_bit_cast(
        bf16x8, *(const uint4*)&Qbh[(size_t)qg * 64 + dd * 16 + hi * 8]);

  f32x16 oacc[2];
#pragma unroll
  for (int dt = 0; dt < 2; ++dt)
#pragma unroll
    for (int r = 0; r < 16; ++r) oacc[dt][r] = 0.f;
  float m_run = -1e38f, l_run = 0.f;

  const int sr = tid >> 3;                    // 0..31
  const int scb = (tid & 7) << 4;             // byte col in 128B row
  const int ssw = (scb ^ ((sr & 7) << 4)) >> 1;  // swizzled ushort col
  const int sc = scb >> 1;                    // source ushort col

  uint4 rk0 = *(const uint4*)&Kbh[(size_t)sr * 64 + sc];
  uint4 rk1 = *(const uint4*)&Kbh[(size_t)(sr + 32) * 64 + sc];
  uint4 rv0 = *(const uint4*)&Vbh[(size_t)sr * 2048 + sc];
  uint4 rv1 = *(const uint4*)&Vbh[(size_t)(sr + 32) * 2048 + sc];

  const int swzm = (ql & 7) << 4;

  for (int kb = 0; kb <= kbmax; ++kb) {
    const int cur = kb & 1;
    unsigned short* K_ = lsKV[cur];
    unsigned short* V_ = lsKV[2 + cur];
    *(uint4*)&K_[sr * 64 + ssw] = rk0;
    *(uint4*)&K_[(sr + 32) * 64 + ssw] = rk1;
    *(uint4*)&V_[sr * 64 + ssw] = rv0;
    *(uint4*)&V_[(sr + 32) * 64 + ssw] = rv1;
    __syncthreads();   // the ONLY barrier per tile: all writes of buf[cur] done
    if (kb < kbmax) {  // prefetch next tile into regs (overlaps compute below)
      const int k0n = (kb + 1) * 64;
      rk0 = *(const uint4*)&Kbh[(size_t)(k0n + sr) * 64 + sc];
      rk1 = *(const uint4*)&Kbh[(size_t)(k0n + sr + 32) * 64 + sc];
      rv0 = *(const uint4*)&Vbh[(size_t)sr * 2048 + k0n + sc];
      rv1 = *(const uint4*)&Vbh[(size_t)(sr + 32) * 2048 + k0n + sc];
    }
    if (kb * 64 <= qwb + 31) {  // wave-uniform causal skip
      f32x16 sacc[2];
#pragma unroll
      for (int kt = 0; kt < 2; ++kt)
#pragma unroll
        for (int r = 0; r < 16; ++r) sacc[kt][r] = 0.f;
      __builtin_amdgcn_s_setprio(1);
#pragma unroll
      for (int kt = 0; kt < 2; ++kt)
#pragma unroll
        for (int dd = 0; dd < 4; ++dd) {
          const int col = (((dd << 5) | (hi << 4)) ^ swzm) >> 1;
          bf16x8 kf = ldsv8(&K_[(kt * 32 + ql) * 64 + col]);
          sacc[kt] = __builtin_amdgcn_mfma_f32_32x32x16_bf16(kf, qf[dd], sacc[kt], 0, 0, 0);
        }
      __builtin_amdgcn_s_setprio(0);
      if (kb * 64 + 63 > qwb) {
#pragma unroll
        for (int kt = 0; kt < 2; ++kt)
#pragma unroll
          for (int r = 0; r < 16; ++r) {
            int key = kb * 64 + kt * 32 + (r & 3) + 8 * (r >> 2) + 4 * hi;
            if (key > qg) sacc[kt][r] = -1e38f;
          }
      }
      // ---- online softmax with defer-max (T13, THR=8)
      float t16[16];
#pragma unroll
      for (int i = 0; i < 16; ++i) t16[i] = fmaxf(sacc[0][i], sacc[1][i]);
#pragma unroll
      for (int i = 0; i < 8; ++i) t16[i] = fmaxf(t16[i], t16[i + 8]);
#pragma unroll
      for (int i = 0; i < 4; ++i) t16[i] = fmaxf(t16[i], t16[i + 4]);
      float mx = fmaxf(fmaxf(t16[0], t16[1]), fmaxf(t16[2], t16[3]));
      mx = fmaxf(mx, __shfl_xor(mx, 32));
      if (!__all(mx <= m_run + 8.0f)) {
        const float mnew = fmaxf(m_run, mx);
        const float alpha = exp2f((m_run - mnew) * 1.44269504f);
        m_run = mnew;
        l_run *= alpha;
#pragma unroll
        for (int dt = 0; dt < 2; ++dt)
#pragma unroll
          for (int r = 0; r < 16; ++r) oacc[dt][r] *= alpha;
      }
#pragma unroll
      for (int kt = 0; kt < 2; ++kt)
#pragma unroll
        for (int r = 0; r < 16; ++r)
          sacc[kt][r] = exp2f((sacc[kt][r] - m_run) * 1.44269504f);
      float s16[16];
#pragma unroll
      for (int i = 0; i < 16; ++i) s16[i] = sacc[0][i] + sacc[1][i];
#pragma unroll
      for (int i = 0; i < 8; ++i) s16[i] += s16[i + 8];
#pragma unroll
      for (int i = 0; i < 4; ++i) s16[i] += s16[i + 4];
      float psum = (s16[0] + s16[1]) + (s16[2] + s16[3]);
      psum += __shfl_xor(psum, 32);
      l_run += psum;
      // ---- P pack + swapped PV
#pragma unroll
      for (int ks = 0; ks < 4; ++ks) {
        const int kt = ks >> 1, s8 = (ks & 1) * 8;
        uint32_t d00 = cvtpk(sacc[kt][s8 + 0], sacc[kt][s8 + 1]);
        uint32_t d01 = cvtpk(sacc[kt][s8 + 2], sacc[kt][s8 + 3]);
        uint32_t d10 = cvtpk(sacc[kt][s8 + 4], sacc[kt][s8 + 5]);
        uint32_t d11 = cvtpk(sacc[kt][s8 + 6], sacc[kt][s8 + 7]);
        plswap(d00, d10);
        plswap(d01, d11);
        uint4 pw;
        pw.x = d00; pw.y = d01; pw.z = d10; pw.w = d11;
        bf16x8 pb = __builtin_bit_cast(bf16x8, pw);
        __builtin_amdgcn_s_setprio(1);
#pragma unroll
        for (int dt = 0; dt < 2; ++dt) {
          const int col = (((ks << 5) | (hi << 4)) ^ swzm) >> 1;
          bf16x8 vf = ldsv8(&V_[(dt * 32 + ql) * 64 + col]);
          oacc[dt] = __builtin_amdgcn_mfma_f32_32x32x16_bf16(vf, pb, oacc[dt], 0, 0, 0);
        }
        __builtin_amdgcn_s_setprio(0);
      }
    }
    // no trailing barrier: next iter writes buf[cur^1], last read two iters ago
  }

  // ---- epilogue: O^T -> LDS transpose -> coalesced store (aliases lsKV space)
  __syncthreads();  // all waves done reading lsKV before we overwrite it
  unsigned short* lsE = &lsKV[0][0];  // [wave][32 rows][72] layout
  const float inv = 1.0f / l_run;
  const int b = bh >> 4, h = bh & 15;
#pragma unroll
  for (int dt = 0; dt < 2; ++dt)
#pragma unroll
    for (int r = 0; r < 16; r += 2) {
      int d0 = dt * 32 + (r & 3) + 8 * (r >> 2) + 4 * hi;
      uint32_t dw = cvtpk(oacc[dt][r] * inv, oacc[dt][r + 1] * inv);
      *(uint32_t*)&lsE[((wid * 32 + ql) * 72) + d0] = dw;
    }
#pragma unroll
  for (int p = 0; p < 4; ++p) {
    int id = p * 64 + lane;
    int rq = id >> 3, ch = (id & 7) * 8;
    uint4 vv = *(const uint4*)&lsE[((wid * 32 + rq) * 72) + ch];
    *(uint4*)&attn[((size_t)(b * 2048 + qwb + rq)) * 1024 + h * 64 + ch] = vv;
  }
}

// ---------- workspace layout (bytes) ----------
//  xb @0 16MB | wqb @16MB 2MB | wkb @18MB 2MB | wvb @20MB 2MB | wob @22MB 2MB
//  Qb @24MB 16MB | Kb @40MB 16MB | Vtb @56MB 16MB | attnb @72MB 16MB

extern "C" void kernel_launch(void* const* d_in, const int* in_sizes, int n_in,
                              void* d_out, int out_size, void* d_ws, size_t ws_size,
                              hipStream_t stream) {
  const float* x = (const float*)d_in[0];
  const float* wq = (const float*)d_in[1];
  const float* wk = (const float*)d_in[2];
  const float* wv = (const float*)d_in[3];
  const float* wo = (const float*)d_in[4];
  float* out = (float*)d_out;

  char* ws = (char*)d_ws;
  unsigned short* xb   = (unsigned short*)(ws + 0);
  unsigned short* wqb  = (unsigned short*)(ws + 16777216);
  unsigned short* wkb  = (unsigned short*)(ws + 18874368);
  unsigned short* wvb  = (unsigned short*)(ws + 20971520);
  unsigned short* wob  = (unsigned short*)(ws + 23068672);
  unsigned short* Qb   = (unsigned short*)(ws + 25165824);
  unsigned short* Kb   = (unsigned short*)(ws + 41943040);
  unsigned short* Vtb  = (unsigned short*)(ws + 58720256);
  unsigned short* attb = (unsigned short*)(ws + 75497472);

  cvt_kernel<<<2048, 256, 0, stream>>>(x, xb, 1048576);
  cvt_w_kernel<<<dim3(256, 4), 256, 0, stream>>>(wq, wk, wv, wo, wqb, wkb, wvb, wob, 131072);

  gemm_qkv_kernel<<<dim3(8, 64, 3), 256, 0, stream>>>(xb, wqb, wkb, wvb, Qb, Kb, Vtb);
  fattn_kernel<<<dim3(64, 16), 256, 0, stream>>>(Qb, Kb, Vtb, attb);
  gemm_ao_kernel<<<dim3(8, 64), 256, 0, stream>>>(attb, wob, out);
}

// Round 10
// 268.445 us; speedup vs baseline: 1.1129x; 1.0438x over previous
//
#include <hip/hip_runtime.h>
#include <hip/hip_bf16.h>
#include <stdint.h>

// ---------- types ----------
typedef __bf16 bf16x8 __attribute__((ext_vector_type(8)));
typedef float  f32x4  __attribute__((ext_vector_type(4)));
typedef float  f32x16 __attribute__((ext_vector_type(16)));

#define AS1(p) (const __attribute__((address_space(1))) uint32_t*)(p)
#define AS3(p) (__attribute__((address_space(3))) uint32_t*)(p)

__device__ __forceinline__ unsigned short f2bf(float f) {
  uint32_t u = __builtin_bit_cast(uint32_t, f);
  u = (u + 0x7fffu + ((u >> 16) & 1u)) >> 16;
  return (unsigned short)u;
}

__device__ __forceinline__ bf16x8 ldsv8(const unsigned short* p) {
  return __builtin_bit_cast(bf16x8, *(const uint4*)p);
}

__device__ __forceinline__ uint32_t cvtpk(float lo, float hi) {
  uint32_t d;
  asm("v_cvt_pk_bf16_f32 %0, %1, %2" : "=v"(d) : "v"(lo), "v"(hi));
  return d;
}

// v_permlane32_swap_b32: a's upper 32 lanes <-> b's lower 32 lanes.
__device__ __forceinline__ void plswap(uint32_t& a, uint32_t& b) {
  asm volatile("v_permlane32_swap_b32 %0, %1" : "+v"(a), "+v"(b));
}

// ---------- fp32 -> bf16 convert (8 elems/thread) ----------
__global__ void cvt_kernel(const float* __restrict__ in,
                           unsigned short* __restrict__ out, int n8) {
  int stride = gridDim.x * blockDim.x;
  for (int i = blockIdx.x * blockDim.x + threadIdx.x; i < n8; i += stride) {
    const float4* p = (const float4*)in + 2 * (size_t)i;
    float4 a = p[0], b = p[1];
    uint4 o;
    o.x = (uint32_t)f2bf(a.x) | ((uint32_t)f2bf(a.y) << 16);
    o.y = (uint32_t)f2bf(a.z) | ((uint32_t)f2bf(a.w) << 16);
    o.z = (uint32_t)f2bf(b.x) | ((uint32_t)f2bf(b.y) << 16);
    o.w = (uint32_t)f2bf(b.z) | ((uint32_t)f2bf(b.w) << 16);
    ((uint4*)out)[i] = o;
  }
}

// ---------- 4 weight matrices in one launch: grid.y selects the pair ----------
__global__ void cvt_w_kernel(const float* __restrict__ w0, const float* __restrict__ w1,
                             const float* __restrict__ w2, const float* __restrict__ w3,
                             unsigned short* __restrict__ o0, unsigned short* __restrict__ o1,
                             unsigned short* __restrict__ o2, unsigned short* __restrict__ o3,
                             int n8) {
  const float* in = (blockIdx.y == 0) ? w0 : (blockIdx.y == 1) ? w1 : (blockIdx.y == 2) ? w2 : w3;
  unsigned short* out = (blockIdx.y == 0) ? o0 : (blockIdx.y == 1) ? o1 : (blockIdx.y == 2) ? o2 : o3;
  int stride = gridDim.x * blockDim.x;
  for (int i = blockIdx.x * blockDim.x + threadIdx.x; i < n8; i += stride) {
    const float4* p = (const float4*)in + 2 * (size_t)i;
    float4 a = p[0], b = p[1];
    uint4 o;
    o.x = (uint32_t)f2bf(a.x) | ((uint32_t)f2bf(a.y) << 16);
    o.y = (uint32_t)f2bf(a.z) | ((uint32_t)f2bf(a.w) << 16);
    o.z = (uint32_t)f2bf(b.x) | ((uint32_t)f2bf(b.y) << 16);
    o.w = (uint32_t)f2bf(b.z) | ((uint32_t)f2bf(b.w) << 16);
    ((uint4*)out)[i] = o;
  }
}

// ---------- QKV projection GEMM: z selects W. BK=64 via k-split LDS [2][128x32] ----------
// 32 MFMA per barrier-pair (2x the BK=32 version); row stride stays 64B -> free 2-way banks.
__global__ __launch_bounds__(256) void gemm_qkv_kernel(
    const unsigned short* __restrict__ X,
    const unsigned short* __restrict__ Wq,
    const unsigned short* __restrict__ Wk,
    const unsigned short* __restrict__ Wv,
    unsigned short* __restrict__ Qo,
    unsigned short* __restrict__ Ko,
    unsigned short* __restrict__ Vt) {
  __shared__ unsigned short lsA[2][128 * 32];
  __shared__ unsigned short lsB[2][128 * 32];
  const int z = blockIdx.z;
  const unsigned short* Bt = (z == 0) ? Wq : (z == 1) ? Wk : Wv;
  const int m0 = blockIdx.y * 128;
  const int n0 = blockIdx.x * 128;
  const int tid = threadIdx.x;
  const int wid = tid >> 6, lane = tid & 63;
  const int wm = wid >> 1, wn = wid & 1;
  const int lrow = lane & 15, lhi = lane >> 4;

  f32x4 acc[4][4];
#pragma unroll
  for (int i = 0; i < 4; ++i)
#pragma unroll
    for (int j = 0; j < 4; ++j) acc[i][j] = f32x4{0.f, 0.f, 0.f, 0.f};

  const int idx = wid * 64 + lane;               // base chunk (c adds 256)
  for (int kt = 0; kt < 1024; kt += 64) {
#pragma unroll
    for (int ks2 = 0; ks2 < 2; ++ks2)
#pragma unroll
      for (int c = 0; c < 2; ++c) {
        const int id2 = idx + c * 256;           // 0..511
        const uint32_t off = (uint32_t)(id2 * 16);
        const uint32_t row = off >> 6, col = (off & 63) >> 1;
        const unsigned short* ga = X + (size_t)(m0 + row) * 1024 + kt + ks2 * 32 + col;
        const unsigned short* gb = Bt + (size_t)(n0 + row) * 1024 + kt + ks2 * 32 + col;
        __builtin_amdgcn_global_load_lds(AS1(ga), AS3(lsA[ks2] + id2 * 8), 16, 0, 0);
        __builtin_amdgcn_global_load_lds(AS1(gb), AS3(lsB[ks2] + id2 * 8), 16, 0, 0);
      }
    __syncthreads();
#pragma unroll
    for (int ks2 = 0; ks2 < 2; ++ks2) {
      bf16x8 af[4], bfv[4];
#pragma unroll
      for (int i = 0; i < 4; ++i)
        af[i] = ldsv8(&lsA[ks2][(wm * 64 + i * 16 + lrow) * 32 + lhi * 8]);
#pragma unroll
      for (int j = 0; j < 4; ++j)
        bfv[j] = ldsv8(&lsB[ks2][(wn * 64 + j * 16 + lrow) * 32 + lhi * 8]);
#pragma unroll
      for (int i = 0; i < 4; ++i)
#pragma unroll
        for (int j = 0; j < 4; ++j)
          acc[i][j] = __builtin_amdgcn_mfma_f32_16x16x32_bf16(af[i], bfv[j], acc[i][j], 0, 0, 0);
    }
    __syncthreads();
  }

  const int b = m0 >> 11;                        // 128-tile never crosses a batch boundary
  if (z == 2) {
    // V^T: pack 4 consecutive-s bf16 into one 8B store per (i,j)
#pragma unroll
    for (int i = 0; i < 4; ++i)
#pragma unroll
      for (int j = 0; j < 4; ++j) {
        int s0 = (m0 + wm * 64 + i * 16 + lhi * 4) & 2047;
        int n = n0 + wn * 64 + j * 16 + lrow;
        int h = n >> 6, dk = n & 63;
        uint2 pk;
        pk.x = (uint32_t)f2bf(acc[i][j][0]) | ((uint32_t)f2bf(acc[i][j][1]) << 16);
        pk.y = (uint32_t)f2bf(acc[i][j][2]) | ((uint32_t)f2bf(acc[i][j][3]) << 16);
        *(uint2*)&Vt[((size_t)(b * 16 + h) * 64 + dk) * 2048 + s0] = pk;
      }
  } else {
    unsigned short* O = (z == 0) ? Qo : Ko;
    const float scale = (z == 0) ? 0.125f : 1.0f;
#pragma unroll
    for (int i = 0; i < 4; ++i)
#pragma unroll
      for (int j = 0; j < 4; ++j)
#pragma unroll
        for (int r = 0; r < 4; ++r) {
          int m = m0 + wm * 64 + i * 16 + lhi * 4 + r;
          int n = n0 + wn * 64 + j * 16 + lrow;
          int s = m & 2047, h = n >> 6, dk = n & 63;
          O[((size_t)(b * 16 + h) * 2048 + s) * 64 + dk] = f2bf(acc[i][j][r] * scale);
        }
  }
}

// ---------- output GEMM: out = attn @ Wo^T (fp32 out), BK=64 k-split ----------
__global__ __launch_bounds__(256) void gemm_ao_kernel(
    const unsigned short* __restrict__ A,
    const unsigned short* __restrict__ Bt,
    float* __restrict__ C) {
  __shared__ unsigned short lsA[2][128 * 32];
  __shared__ unsigned short lsB[2][128 * 32];
  const int m0 = blockIdx.y * 128;
  const int n0 = blockIdx.x * 128;
  const int tid = threadIdx.x;
  const int wid = tid >> 6, lane = tid & 63;
  const int wm = wid >> 1, wn = wid & 1;
  const int lrow = lane & 15, lhi = lane >> 4;

  f32x4 acc[4][4];
#pragma unroll
  for (int i = 0; i < 4; ++i)
#pragma unroll
    for (int j = 0; j < 4; ++j) acc[i][j] = f32x4{0.f, 0.f, 0.f, 0.f};

  const int idx = wid * 64 + lane;
  for (int kt = 0; kt < 1024; kt += 64) {
#pragma unroll
    for (int ks2 = 0; ks2 < 2; ++ks2)
#pragma unroll
      for (int c = 0; c < 2; ++c) {
        const int id2 = idx + c * 256;
        const uint32_t off = (uint32_t)(id2 * 16);
        const uint32_t row = off >> 6, col = (off & 63) >> 1;
        const unsigned short* ga = A + (size_t)(m0 + row) * 1024 + kt + ks2 * 32 + col;
        const unsigned short* gb = Bt + (size_t)(n0 + row) * 1024 + kt + ks2 * 32 + col;
        __builtin_amdgcn_global_load_lds(AS1(ga), AS3(lsA[ks2] + id2 * 8), 16, 0, 0);
        __builtin_amdgcn_global_load_lds(AS1(gb), AS3(lsB[ks2] + id2 * 8), 16, 0, 0);
      }
    __syncthreads();
#pragma unroll
    for (int ks2 = 0; ks2 < 2; ++ks2) {
      bf16x8 af[4], bfv[4];
#pragma unroll
      for (int i = 0; i < 4; ++i)
        af[i] = ldsv8(&lsA[ks2][(wm * 64 + i * 16 + lrow) * 32 + lhi * 8]);
#pragma unroll
      for (int j = 0; j < 4; ++j)
        bfv[j] = ldsv8(&lsB[ks2][(wn * 64 + j * 16 + lrow) * 32 + lhi * 8]);
#pragma unroll
      for (int i = 0; i < 4; ++i)
#pragma unroll
        for (int j = 0; j < 4; ++j)
          acc[i][j] = __builtin_amdgcn_mfma_f32_16x16x32_bf16(af[i], bfv[j], acc[i][j], 0, 0, 0);
    }
    __syncthreads();
  }

#pragma unroll
  for (int i = 0; i < 4; ++i)
#pragma unroll
    for (int j = 0; j < 4; ++j)
#pragma unroll
      for (int r = 0; r < 4; ++r) {
        int m = m0 + wm * 64 + i * 16 + lhi * 4 + r;
        int n = n0 + wn * 64 + j * 16 + lrow;
        C[(size_t)m * 1024 + n] = acc[i][j][r];
      }
}

// ---------- flash attention: swapped 32x32 MFMA, dbuf K/V, ONE barrier per KV tile ----------
// Grid: (64 bh FAST, 16 qsy) -> gid%8 = bh%8 spreads each causal class over all XCDs.
__global__ __launch_bounds__(256, 3) void fattn_kernel(
    const unsigned short* __restrict__ Q,
    const unsigned short* __restrict__ K,
    const unsigned short* __restrict__ Vt,
    unsigned short* __restrict__ attn) {
  __shared__ unsigned short lsKV[4][64 * 64];

  const int qs = 15 - (int)blockIdx.y;        // heavy classes launch first
  const int bh = blockIdx.x;
  const int tid = threadIdx.x, wid = tid >> 6, lane = tid & 63;
  const int ql = lane & 31, hi = lane >> 5;
  const int qwb = qs * 128 + wid * 32;        // wave's q base
  const int qg = qwb + ql;                    // this lane's q row
  const int kbmax = 2 * qs + 1;

  const unsigned short* Qbh = Q + (size_t)bh * 2048 * 64;
  const unsigned short* Kbh = K + (size_t)bh * 2048 * 64;
  const unsigned short* Vbh = Vt + (size_t)bh * 64 * 2048;

  bf16x8 qf[4];
#pragma unroll
  for (int dd = 0; dd < 4; ++dd)
    qf[dd] = __builtin_bit_cast(
        bf16x8, *(const uint4*)&Qbh[(size_t)qg * 64 + dd * 16 + hi * 8]);

  f32x16 oacc[2];
#pragma unroll
  for (int dt = 0; dt < 2; ++dt)
#pragma unroll
    for (int r = 0; r < 16; ++r) oacc[dt][r] = 0.f;
  float m_run = -1e38f, l_run = 0.f;

  const int sr = tid >> 3;                    // 0..31
  const int scb = (tid & 7) << 4;             // byte col in 128B row
  const int ssw = (scb ^ ((sr & 7) << 4)) >> 1;  // swizzled ushort col
  const int sc = scb >> 1;                    // source ushort col

  uint4 rk0 = *(const uint4*)&Kbh[(size_t)sr * 64 + sc];
  uint4 rk1 = *(const uint4*)&Kbh[(size_t)(sr + 32) * 64 + sc];
  uint4 rv0 = *(const uint4*)&Vbh[(size_t)sr * 2048 + sc];
  uint4 rv1 = *(const uint4*)&Vbh[(size_t)(sr + 32) * 2048 + sc];

  const int swzm = (ql & 7) << 4;

  for (int kb = 0; kb <= kbmax; ++kb) {
    const int cur = kb & 1;
    unsigned short* K_ = lsKV[cur];
    unsigned short* V_ = lsKV[2 + cur];
    *(uint4*)&K_[sr * 64 + ssw] = rk0;
    *(uint4*)&K_[(sr + 32) * 64 + ssw] = rk1;
    *(uint4*)&V_[sr * 64 + ssw] = rv0;
    *(uint4*)&V_[(sr + 32) * 64 + ssw] = rv1;
    __syncthreads();   // the ONLY barrier per tile: all writes of buf[cur] done
    if (kb < kbmax) {  // prefetch next tile into regs (overlaps compute below)
      const int k0n = (kb + 1) * 64;
      rk0 = *(const uint4*)&Kbh[(size_t)(k0n + sr) * 64 + sc];
      rk1 = *(const uint4*)&Kbh[(size_t)(k0n + sr + 32) * 64 + sc];
      rv0 = *(const uint4*)&Vbh[(size_t)sr * 2048 + k0n + sc];
      rv1 = *(const uint4*)&Vbh[(size_t)(sr + 32) * 2048 + k0n + sc];
    }
    if (kb * 64 <= qwb + 31) {  // wave-uniform causal skip
      f32x16 sacc[2];
#pragma unroll
      for (int kt = 0; kt < 2; ++kt)
#pragma unroll
        for (int r = 0; r < 16; ++r) sacc[kt][r] = 0.f;
      __builtin_amdgcn_s_setprio(1);
#pragma unroll
      for (int kt = 0; kt < 2; ++kt)
#pragma unroll
        for (int dd = 0; dd < 4; ++dd) {
          const int col = (((dd << 5) | (hi << 4)) ^ swzm) >> 1;
          bf16x8 kf = ldsv8(&K_[(kt * 32 + ql) * 64 + col]);
          sacc[kt] = __builtin_amdgcn_mfma_f32_32x32x16_bf16(kf, qf[dd], sacc[kt], 0, 0, 0);
        }
      __builtin_amdgcn_s_setprio(0);
      if (kb * 64 + 63 > qwb) {
#pragma unroll
        for (int kt = 0; kt < 2; ++kt)
#pragma unroll
          for (int r = 0; r < 16; ++r) {
            int key = kb * 64 + kt * 32 + (r & 3) + 8 * (r >> 2) + 4 * hi;
            if (key > qg) sacc[kt][r] = -1e38f;
          }
      }
      // ---- online softmax with defer-max (T13, THR=8)
      float t16[16];
#pragma unroll
      for (int i = 0; i < 16; ++i) t16[i] = fmaxf(sacc[0][i], sacc[1][i]);
#pragma unroll
      for (int i = 0; i < 8; ++i) t16[i] = fmaxf(t16[i], t16[i + 8]);
#pragma unroll
      for (int i = 0; i < 4; ++i) t16[i] = fmaxf(t16[i], t16[i + 4]);
      float mx = fmaxf(fmaxf(t16[0], t16[1]), fmaxf(t16[2], t16[3]));
      mx = fmaxf(mx, __shfl_xor(mx, 32));
      if (!__all(mx <= m_run + 8.0f)) {
        const float mnew = fmaxf(m_run, mx);
        const float alpha = exp2f((m_run - mnew) * 1.44269504f);
        m_run = mnew;
        l_run *= alpha;
#pragma unroll
        for (int dt = 0; dt < 2; ++dt)
#pragma unroll
          for (int r = 0; r < 16; ++r) oacc[dt][r] *= alpha;
      }
#pragma unroll
      for (int kt = 0; kt < 2; ++kt)
#pragma unroll
        for (int r = 0; r < 16; ++r)
          sacc[kt][r] = exp2f((sacc[kt][r] - m_run) * 1.44269504f);
      float s16[16];
#pragma unroll
      for (int i = 0; i < 16; ++i) s16[i] = sacc[0][i] + sacc[1][i];
#pragma unroll
      for (int i = 0; i < 8; ++i) s16[i] += s16[i + 8];
#pragma unroll
      for (int i = 0; i < 4; ++i) s16[i] += s16[i + 4];
      float psum = (s16[0] + s16[1]) + (s16[2] + s16[3]);
      psum += __shfl_xor(psum, 32);
      l_run += psum;
      // ---- P pack + swapped PV
#pragma unroll
      for (int ks = 0; ks < 4; ++ks) {
        const int kt = ks >> 1, s8 = (ks & 1) * 8;
        uint32_t d00 = cvtpk(sacc[kt][s8 + 0], sacc[kt][s8 + 1]);
        uint32_t d01 = cvtpk(sacc[kt][s8 + 2], sacc[kt][s8 + 3]);
        uint32_t d10 = cvtpk(sacc[kt][s8 + 4], sacc[kt][s8 + 5]);
        uint32_t d11 = cvtpk(sacc[kt][s8 + 6], sacc[kt][s8 + 7]);
        plswap(d00, d10);
        plswap(d01, d11);
        uint4 pw;
        pw.x = d00; pw.y = d01; pw.z = d10; pw.w = d11;
        bf16x8 pb = __builtin_bit_cast(bf16x8, pw);
        __builtin_amdgcn_s_setprio(1);
#pragma unroll
        for (int dt = 0; dt < 2; ++dt) {
          const int col = (((ks << 5) | (hi << 4)) ^ swzm) >> 1;
          bf16x8 vf = ldsv8(&V_[(dt * 32 + ql) * 64 + col]);
          oacc[dt] = __builtin_amdgcn_mfma_f32_32x32x16_bf16(vf, pb, oacc[dt], 0, 0, 0);
        }
        __builtin_amdgcn_s_setprio(0);
      }
    }
    // no trailing barrier: next iter writes buf[cur^1], last read two iters ago
  }

  // ---- epilogue: O^T -> LDS transpose -> coalesced store (aliases lsKV space)
  __syncthreads();  // all waves done reading lsKV before we overwrite it
  unsigned short* lsE = &lsKV[0][0];  // [wave][32 rows][72] layout
  const float inv = 1.0f / l_run;
  const int b = bh >> 4, h = bh & 15;
#pragma unroll
  for (int dt = 0; dt < 2; ++dt)
#pragma unroll
    for (int r = 0; r < 16; r += 2) {
      int d0 = dt * 32 + (r & 3) + 8 * (r >> 2) + 4 * hi;
      uint32_t dw = cvtpk(oacc[dt][r] * inv, oacc[dt][r + 1] * inv);
      *(uint32_t*)&lsE[((wid * 32 + ql) * 72) + d0] = dw;
    }
#pragma unroll
  for (int p = 0; p < 4; ++p) {
    int id = p * 64 + lane;
    int rq = id >> 3, ch = (id & 7) * 8;
    uint4 vv = *(const uint4*)&lsE[((wid * 32 + rq) * 72) + ch];
    *(uint4*)&attn[((size_t)(b * 2048 + qwb + rq)) * 1024 + h * 64 + ch] = vv;
  }
}

// ---------- workspace layout (bytes) ----------
//  xb @0 16MB | wqb @16MB 2MB | wkb @18MB 2MB | wvb @20MB 2MB | wob @22MB 2MB
//  Qb @24MB 16MB | Kb @40MB 16MB | Vtb @56MB 16MB | attnb @72MB 16MB

extern "C" void kernel_launch(void* const* d_in, const int* in_sizes, int n_in,
                              void* d_out, int out_size, void* d_ws, size_t ws_size,
                              hipStream_t stream) {
  const float* x = (const float*)d_in[0];
  const float* wq = (const float*)d_in[1];
  const float* wk = (const float*)d_in[2];
  const float* wv = (const float*)d_in[3];
  const float* wo = (const float*)d_in[4];
  float* out = (float*)d_out;

  char* ws = (char*)d_ws;
  unsigned short* xb   = (unsigned short*)(ws + 0);
  unsigned short* wqb  = (unsigned short*)(ws + 16777216);
  unsigned short* wkb  = (unsigned short*)(ws + 18874368);
  unsigned short* wvb  = (unsigned short*)(ws + 20971520);
  unsigned short* wob  = (unsigned short*)(ws + 23068672);
  unsigned short* Qb   = (unsigned short*)(ws + 25165824);
  unsigned short* Kb   = (unsigned short*)(ws + 41943040);
  unsigned short* Vtb  = (unsigned short*)(ws + 58720256);
  unsigned short* attb = (unsigned short*)(ws + 75497472);

  cvt_kernel<<<2048, 256, 0, stream>>>(x, xb, 1048576);
  cvt_w_kernel<<<dim3(256, 4), 256, 0, stream>>>(wq, wk, wv, wo, wqb, wkb, wvb, wob, 131072);

  gemm_qkv_kernel<<<dim3(8, 64, 3), 256, 0, stream>>>(xb, wqb, wkb, wvb, Qb, Kb, Vtb);
  fattn_kernel<<<dim3(64, 16), 256, 0, stream>>>(Qb, Kb, Vtb, attb);
  gemm_ao_kernel<<<dim3(8, 64), 256, 0, stream>>>(attb, wob, out);
}